// Round 12
// baseline (275.877 us; speedup 1.0000x reference)
//
#include <hip/hip_runtime.h>
#include <math.h>

#define B_ 32
#define N_ 4096
#define D_ 64
#define T_ 12
#define EPS_ 1e-7f
#define PSTR 65
#define ESTR 72   // e-plane LDS row stride in SHORTS (144B, 16B-aligned; 4-way worst)

typedef float4 f4;
#define LD4(p) (*(const float4*)(p))

typedef __attribute__((ext_vector_type(8))) short short8;
typedef __attribute__((ext_vector_type(4))) short s4b;
typedef __attribute__((ext_vector_type(4))) float f32x4;
#define MFMA(a, b, c)   __builtin_amdgcn_mfma_f32_16x16x32_bf16(a, b, c, 0, 0, 0)
#define MFMA16(a, b, c) __builtin_amdgcn_mfma_f32_16x16x16bf16_1k(a, b, c, 0, 0, 0)

// weight blob offsets (shorts) in global wblob
#define OFF_C1H 0
#define OFF_C1L 8192
#define OFF_B1H 16384
#define OFF_B1L 24576
#define OFF_C2TH 32768
#define OFF_C2TL 36864
#define OFF_B2TH 40960
#define OFF_B2TL 45056
#define WBLOB_SHORTS 49152

__device__ __forceinline__ float f4c(const float4 v, int q) {
    return q == 0 ? v.x : q == 1 ? v.y : q == 2 ? v.z : v.w;
}
__device__ __forceinline__ void fma8(float (&acc)[8], float a, const float4 w0, const float4 w1) {
    acc[0] = fmaf(a, w0.x, acc[0]); acc[1] = fmaf(a, w0.y, acc[1]);
    acc[2] = fmaf(a, w0.z, acc[2]); acc[3] = fmaf(a, w0.w, acc[3]);
    acc[4] = fmaf(a, w1.x, acc[4]); acc[5] = fmaf(a, w1.y, acc[5]);
    acc[6] = fmaf(a, w1.z, acc[6]); acc[7] = fmaf(a, w1.w, acc[7]);
}

__device__ __forceinline__ void splitbf(float a, short& h, short& l) {
    unsigned x = __float_as_uint(a);
    h = (short)(x >> 16);
    float r = a - __uint_as_float(x & 0xffff0000u);
    l = (short)(__float_as_uint(r) >> 16);
}

// sigma: involutive feature permutation for e-storage (swap bits[5:4]<->[3:2])
__device__ __forceinline__ int sigma_(int f) {
    return (((f >> 2) & 3) << 4) | (((f >> 4) & 3) << 2) | (f & 3);
}

// ---------------------------------------------------------------------------
// Prep: pack weights (hi/lo planes) into one contiguous blob + bn contrib.
// ---------------------------------------------------------------------------
__global__ void prep_kernel(
    const float* __restrict__ cn_w1, const float* __restrict__ cn_w2,
    const float* __restrict__ bn_w1, const float* __restrict__ bn_w2,
    const float* __restrict__ bn_b1, const float* __restrict__ label_emb,
    short* __restrict__ wblob, float* __restrict__ contrib)
{
    const int tid = threadIdx.x;
    for (int idx = tid; idx < 8192; idx += 256) {   // w1 packs (K=128)
        const int e = idx & 7, l = (idx >> 3) & 63, fb = idx >> 9;
        const int kt = fb >> 2, mt = fb & 3;
        const int f_lin = (kt & 1) * 32 + (l >> 4) * 8 + e;
        const int k = (kt >> 1) * 64 + sigma_(f_lin);
        const int n = mt * 16 + (l & 15);
        short h, lo;
        splitbf(cn_w1[k * 64 + n], h, lo);
        wblob[OFF_C1H + idx] = h; wblob[OFF_C1L + idx] = lo;
        splitbf(bn_w1[k * 64 + n], h, lo);
        wblob[OFF_B1H + idx] = h; wblob[OFF_B1L + idx] = lo;
    }
    for (int idx = tid; idx < 4096; idx += 256) {   // w2^T packs (16x16x16 A)
        const int e = idx & 3, l = (idx >> 2) & 63, fb = idx >> 8;
        const int ks = fb >> 2, mt2 = fb & 3;
        const int k = ks * 16 + (l >> 4) * 4 + e;
        const int n = mt2 * 16 + (l & 15);
        short h, lo;
        splitbf(cn_w2[k * 64 + n], h, lo);
        wblob[OFF_C2TH + idx] = h; wblob[OFF_C2TL + idx] = lo;
        splitbf(bn_w2[k * 64 + n], h, lo);
        wblob[OFF_B2TH + idx] = h; wblob[OFF_B2TL + idx] = lo;
    }
    if (tid < 128) {
        const int c = tid >> 6, n = tid & 63;
        float s = bn_b1[n];
        for (int kk = 0; kk < 64; ++kk)
            s = fmaf(label_emb[c * 64 + kk], bn_w1[(128 + kk) * 64 + n], s);
        contrib[c * 64 + n] = s;
    }
}

// ---------------------------------------------------------------------------
// Embedding (fp32 vector). Writes e as bf16 hi/lo planes in sigma order.
// ---------------------------------------------------------------------------
__global__ __launch_bounds__(256, 4) void emb_kernel(
    const int* __restrict__ x, const float* __restrict__ y,
    const float* __restrict__ w1, const float* __restrict__ b1,
    const float* __restrict__ w2, const float* __restrict__ b2,
    short* __restrict__ e_hi, short* __restrict__ e_lo, int* __restrict__ v_out)
{
    __shared__ float h_lds[128 * PSTR];
    const int tid = threadIdx.x;
    const int s   = tid & 7;
    const int g   = tid >> 3;
    const int jj0 = s * 8;
    const int i0  = (blockIdx.x * 32 + g) * 4;

    {
        f4 wa0 = LD4(w1 + jj0),      wa1 = LD4(w1 + jj0 + 4);
        f4 wb0 = LD4(w1 + D_ + jj0), wb1 = LD4(w1 + D_ + jj0 + 4);
        f4 bb0 = LD4(b1 + jj0),      bb1 = LD4(b1 + jj0 + 4);
#pragma unroll
        for (int pp = 0; pp < 4; ++pp) {
            const float2 yv = *(const float2*)(y + 2 * (i0 + pp));
            f4 h0, h1;
            h0.x = fmaxf(fmaf(yv.y, wb0.x, fmaf(yv.x, wa0.x, bb0.x)), 0.f);
            h0.y = fmaxf(fmaf(yv.y, wb0.y, fmaf(yv.x, wa0.y, bb0.y)), 0.f);
            h0.z = fmaxf(fmaf(yv.y, wb0.z, fmaf(yv.x, wa0.z, bb0.z)), 0.f);
            h0.w = fmaxf(fmaf(yv.y, wb0.w, fmaf(yv.x, wa0.w, bb0.w)), 0.f);
            h1.x = fmaxf(fmaf(yv.y, wb1.x, fmaf(yv.x, wa1.x, bb1.x)), 0.f);
            h1.y = fmaxf(fmaf(yv.y, wb1.y, fmaf(yv.x, wa1.y, bb1.y)), 0.f);
            h1.z = fmaxf(fmaf(yv.y, wb1.z, fmaf(yv.x, wa1.z, bb1.z)), 0.f);
            h1.w = fmaxf(fmaf(yv.y, wb1.w, fmaf(yv.x, wa1.w, bb1.w)), 0.f);
            float* hp = h_lds + (g * 4 + pp) * PSTR + jj0;
            *(f4*)hp = h0; *(f4*)(hp + 4) = h1;
        }
    }
    __syncthreads();

    float o[4][8];
    {
        f4 b20 = LD4(b2 + jj0), b21 = LD4(b2 + jj0 + 4);
#pragma unroll
        for (int pp = 0; pp < 4; ++pp) {
            o[pp][0]=b20.x; o[pp][1]=b20.y; o[pp][2]=b20.z; o[pp][3]=b20.w;
            o[pp][4]=b21.x; o[pp][5]=b21.y; o[pp][6]=b21.z; o[pp][7]=b21.w;
        }
    }
#pragma unroll 2
    for (int k4 = 0; k4 < 16; ++k4) {
        const f4 x0 = LD4(h_lds + (g * 4 + 0) * PSTR + 4 * k4);
        const f4 x1 = LD4(h_lds + (g * 4 + 1) * PSTR + 4 * k4);
        const f4 x2 = LD4(h_lds + (g * 4 + 2) * PSTR + 4 * k4);
        const f4 x3 = LD4(h_lds + (g * 4 + 3) * PSTR + 4 * k4);
        const float* wk = w2 + (4 * k4) * D_ + jj0;
#pragma unroll
        for (int q = 0; q < 4; ++q) {
            const f4 wa = LD4(wk + q * D_), wb = LD4(wk + q * D_ + 4);
            fma8(o[0], f4c(x0, q), wa, wb);
            fma8(o[1], f4c(x1, q), wa, wb);
            fma8(o[2], f4c(x2, q), wa, wb);
            fma8(o[3], f4c(x3, q), wa, wb);
        }
    }

    const int sp0 = (((jj0 >> 2) & 3) << 4) | (((jj0 >> 4) & 3) << 2);
    const int sp1 = ((((jj0 + 4) >> 2) & 3) << 4) | ((((jj0 + 4) >> 4) & 3) << 2);
#pragma unroll
    for (int pp = 0; pp < 4; ++pp) {
        const size_t rb = (size_t)(i0 + pp) * D_;
        union { short s[8]; uint2 v[2]; } uh, ul;
#pragma unroll
        for (int q = 0; q < 8; ++q) splitbf(o[pp][q], uh.s[q], ul.s[q]);
        *(uint2*)(e_hi + rb + sp0) = uh.v[0];
        *(uint2*)(e_hi + rb + sp1) = uh.v[1];
        *(uint2*)(e_lo + rb + sp0) = ul.v[0];
        *(uint2*)(e_lo + rb + sp1) = ul.v[1];
    }
    if (s < 4) v_out[i0 + s] = x[i0 + s];
}

// ---------------------------------------------------------------------------
// Global tree stage (t = 0..4): W1 in registers (own net per wave),
// W2^T in LDS (32KB), e streamed from global. 512 thr = 8 waves:
// net = wid>>2, each wave 32 pairs (2 M-subtiles). Block = 128 pairs.
// ---------------------------------------------------------------------------
__global__ __launch_bounds__(512, 2) void stage_kernel(
    const short* __restrict__ e_hi, const short* __restrict__ e_lo,
    const int* __restrict__ v_in,
    short* __restrict__ eo_hi, short* __restrict__ eo_lo, int* __restrict__ v_out,
    const short* __restrict__ wblob,
    const float* __restrict__ cn_b1, const float* __restrict__ cn_b2,
    const float* __restrict__ bn_b2, const float* __restrict__ contrib,
    const float* __restrict__ llr_w, const float* __restrict__ llr_b,
    float* __restrict__ loss_out, float2* __restrict__ pscr,
    int t, int log2Lh)
{
    __shared__ __align__(16) short w2lds[16384];   // 32 KB: c2th|c2tl|b2th|b2tl
    const int tid = threadIdx.x;
    {
        uint4* dst = (uint4*)w2lds;
        const uint4* src = (const uint4*)(wblob + OFF_C2TH);
#pragma unroll
        for (int i = 0; i < 4; ++i)
            dst[tid + i * 512] = src[tid + i * 512];
    }
    const int lane = tid & 63;
    const int pr = lane & 15, kg = lane >> 4;
    const int wid = tid >> 6;
    const int net = wid >> 2, sg = wid & 3;
    const int w2b = net * 8192;

    // hoist own-net layer-1 weight fragments into registers
    short8 w1h[16], w1l[16];
    {
        const short* wh = wblob + (net ? OFF_B1H : OFF_C1H);
        const short* wl = wblob + (net ? OFF_B1L : OFF_C1L);
#pragma unroll
        for (int f = 0; f < 16; ++f) {
            const int fo = (f * 64 + lane) * 8;
            w1h[f] = *(const short8*)(wh + fo);
            w1l[f] = *(const short8*)(wl + fo);
        }
    }
    const float* __restrict__ b2 = net ? bn_b2 : cn_b2;
    __syncthreads();

    const int Lh = 1 << log2Lh;
    const int gp0 = blockIdx.x * 128 + sg * 32;

    int gpA[2], v1A[2], vxA[2];
    f32x4 acc[2][4];
#pragma unroll
    for (int s = 0; s < 2; ++s) {
        const int gp = gp0 + s * 16 + pr;
        gpA[s] = gp;
        const int2 vv = *(const int2*)(v_in + 2 * gp);
        v1A[s] = vv.y; vxA[s] = (vv.x ^ vv.y) & 1;
#pragma unroll
        for (int mt = 0; mt < 4; ++mt) {
            if (net) {
                const f4 cb = LD4(contrib + vxA[s] * 64 + mt * 16 + kg * 4);
                acc[s][mt] = (f32x4){cb.x, cb.y, cb.z, cb.w};
            } else {
                const f4 bc = LD4(cn_b1 + mt * 16 + kg * 4);
                acc[s][mt] = (f32x4){bc.x, bc.y, bc.z, bc.w};
            }
        }
    }

#pragma unroll
    for (int kt = 0; kt < 4; ++kt) {
        short8 Eh[2], El[2];
#pragma unroll
        for (int s = 0; s < 2; ++s) {
            const size_t pos = (size_t)(2 * gpA[s] + (kt >> 1));
            const int off = (kt & 1) * 32 + kg * 8;
            Eh[s] = *(const short8*)(e_hi + pos * D_ + off);
            El[s] = *(const short8*)(e_lo + pos * D_ + off);
        }
#pragma unroll
        for (int mt = 0; mt < 4; ++mt) {
            const short8 wh = w1h[kt * 4 + mt], wl = w1l[kt * 4 + mt];
#pragma unroll
            for (int s = 0; s < 2; ++s) {
                acc[s][mt] = MFMA(wh, Eh[s], acc[s][mt]);
                acc[s][mt] = MFMA(wl, Eh[s], acc[s][mt]);
                acc[s][mt] = MFMA(wh, El[s], acc[s][mt]);
            }
        }
    }

    // relu + split (lane-local 16x16x16 B-frags)
    s4b hh[2][4], hl[2][4];
#pragma unroll
    for (int s = 0; s < 2; ++s)
#pragma unroll
        for (int ks = 0; ks < 4; ++ks)
#pragma unroll
            for (int e2 = 0; e2 < 4; ++e2) {
                short sh, sl2;
                splitbf(fmaxf(acc[s][ks][e2], 0.f), sh, sl2);
                hh[s][ks][e2] = sh; hl[s][ks][e2] = sl2;
            }

    f32x4 o[2][4];
#pragma unroll
    for (int mt2 = 0; mt2 < 4; ++mt2) {
        const f4 bb = LD4(b2 + mt2 * 16 + kg * 4);
#pragma unroll
        for (int s = 0; s < 2; ++s) o[s][mt2] = (f32x4){bb.x, bb.y, bb.z, bb.w};
    }
#pragma unroll
    for (int ks = 0; ks < 4; ++ks)
#pragma unroll
        for (int mt2 = 0; mt2 < 4; ++mt2) {
            const int fo4 = ((ks * 4 + mt2) * 64 + lane) * 4;
            const s4b wh = *(const s4b*)(w2lds + w2b + fo4);
            const s4b wl = *(const s4b*)(w2lds + w2b + 4096 + fo4);
#pragma unroll
            for (int s = 0; s < 2; ++s) {
                o[s][mt2] = MFMA16(wh, hh[s][ks], o[s][mt2]);
                o[s][mt2] = MFMA16(wl, hh[s][ks], o[s][mt2]);
                o[s][mt2] = MFMA16(wh, hl[s][ks], o[s][mt2]);
            }
        }

#pragma unroll
    for (int s = 0; s < 2; ++s) {
        const int gp = gpA[s];
        const int P  = gp & 2047;
        const int j  = P & (Lh - 1);
        const int io = 2 * P - j + (net ? Lh : 0);
        const int b  = gp >> 11;
        const int gout = b * N_ + io;

        float z0 = 0.f, z1 = 0.f;
        union { short sv[16]; uint4 v[2]; } ph, pl;
#pragma unroll
        for (int mt2 = 0; mt2 < 4; ++mt2) {
#pragma unroll
            for (int e2 = 0; e2 < 4; ++e2) {
                short sh, sl2;
                splitbf(o[s][mt2][e2], sh, sl2);
                ph.sv[mt2 * 4 + e2] = sh; pl.sv[mt2 * 4 + e2] = sl2;
            }
            const int f0 = mt2 * 16 + kg * 4;
            const f4 wA = LD4(llr_w + 2 * f0);
            const f4 wB = LD4(llr_w + 2 * f0 + 4);
            z0 += o[s][mt2][0] * wA.x + o[s][mt2][1] * wA.z +
                  o[s][mt2][2] * wB.x + o[s][mt2][3] * wB.z;
            z1 += o[s][mt2][0] * wA.y + o[s][mt2][1] * wA.w +
                  o[s][mt2][2] * wB.y + o[s][mt2][3] * wB.w;
        }
        z0 += __shfl_xor(z0, 16); z1 += __shfl_xor(z1, 16);
        z0 += __shfl_xor(z0, 32); z1 += __shfl_xor(z1, 32);

        const size_t eb = (size_t)gout * D_ + kg * 16;
        *(uint4*)(eo_hi + eb)     = ph.v[0];
        *(uint4*)(eo_hi + eb + 8) = ph.v[1];
        *(uint4*)(eo_lo + eb)     = pl.v[0];
        *(uint4*)(eo_lo + eb + 8) = pl.v[1];

        if (kg == 0) {
            v_out[gout] = net ? v1A[s] : vxA[s];
            const float zz0 = z0 + llr_b[0], zz1 = z1 + llr_b[1];
            const float m   = fmaxf(zz0, zz1);
            const float ex0 = expf(zz0 - m), ex1 = expf(zz1 - m);
            const float inv = 1.0f / (ex0 + ex1);
            const float p0s = ex0 * inv, p1s = ex1 * inv;
            const float c0  = fminf(fmaxf(p0s, EPS_), 1.0f - EPS_);
            const float c1  = fminf(fmaxf(p1s, EPS_), 1.0f - EPS_);
            const int   lab = net ? (v1A[s] & 1) : vxA[s];
            const float loss = -logf(lab ? c1 : c0);
            loss_out[(b * T_ + t) * N_ + io] = loss;
            pscr[(size_t)(b * T_ + t) * N_ + io] = make_float2(p0s, p1s);
        }
    }
}

// ---------------------------------------------------------------------------
// Fused tail (t = 5..11): W1 in registers; LDS = W2 (32KB) + e hi/lo planes
// (36.9KB) + v. 256 thr = 4 waves x (net, 32 pairs). 69.4KB -> 2 blocks/CU.
// ---------------------------------------------------------------------------
__global__ __launch_bounds__(256, 2) void fused_tail(
    const short* __restrict__ e_hi, const short* __restrict__ e_lo,
    const int* __restrict__ v_in,
    const short* __restrict__ wblob,
    const float* __restrict__ cn_b1, const float* __restrict__ cn_b2,
    const float* __restrict__ bn_b2, const float* __restrict__ contrib,
    const float* __restrict__ llr_w, const float* __restrict__ llr_b,
    float* __restrict__ loss_out, float2* __restrict__ pscr)
{
    __shared__ __align__(16) short w2lds[16384];       // 32 KB
    __shared__ __align__(16) short ehl[2][128 * ESTR]; // 2 x 18KB hi/lo planes
    __shared__ int v_lds[128];
    const int tid = threadIdx.x;
    {
        uint4* dst = (uint4*)w2lds;
        const uint4* src = (const uint4*)(wblob + OFF_C2TH);
#pragma unroll
        for (int i = 0; i < 8; ++i)
            dst[tid + i * 256] = src[tid + i * 256];
    }
    const int b = blockIdx.x >> 5, ch = blockIdx.x & 31;
    const int base_row = b * N_ + ch * 128;
    {
        const int r = tid >> 1, seg = tid & 1;
        const size_t g = (size_t)(base_row + r) * D_ + seg * 32;
#pragma unroll
        for (int pl = 0; pl < 2; ++pl) {
            const short* sp = (pl ? e_lo : e_hi) + g;
            short* dp = &ehl[pl][r * ESTR + seg * 32];
            *(uint4*)dp        = *(const uint4*)sp;
            *(uint4*)(dp + 8)  = *(const uint4*)(sp + 8);
            *(uint4*)(dp + 16) = *(const uint4*)(sp + 16);
            *(uint4*)(dp + 24) = *(const uint4*)(sp + 24);
        }
        if (tid < 128) v_lds[tid] = v_in[base_row + tid];
    }

    const int lane = tid & 63;
    const int pr = lane & 15, kg = lane >> 4;
    const int wid = tid >> 6;
    const int net = wid >> 1, sg = wid & 1;
    const int w2b = net * 8192;

    short8 w1h[16], w1l[16];
    {
        const short* wh = wblob + (net ? OFF_B1H : OFF_C1H);
        const short* wl = wblob + (net ? OFF_B1L : OFF_C1L);
#pragma unroll
        for (int f = 0; f < 16; ++f) {
            const int fo = (f * 64 + lane) * 8;
            w1h[f] = *(const short8*)(wh + fo);
            w1l[f] = *(const short8*)(wl + fo);
        }
    }
    const float* __restrict__ b2 = net ? bn_b2 : cn_b2;
    __syncthreads();

    int Lh = 64;
#pragma unroll 1
    for (int t = 5; t < 12; ++t, Lh >>= 1) {
        int pA[2], v1A[2], vxA[2];
        f32x4 acc[2][4];
#pragma unroll
        for (int s = 0; s < 2; ++s) {
            const int p = sg * 32 + s * 16 + pr;
            pA[s] = p;
            const int v0 = v_lds[2 * p], v1 = v_lds[2 * p + 1];
            v1A[s] = v1; vxA[s] = (v0 ^ v1) & 1;
#pragma unroll
            for (int mt = 0; mt < 4; ++mt) {
                if (net) {
                    const f4 cb = LD4(contrib + vxA[s] * 64 + mt * 16 + kg * 4);
                    acc[s][mt] = (f32x4){cb.x, cb.y, cb.z, cb.w};
                } else {
                    const f4 bc = LD4(cn_b1 + mt * 16 + kg * 4);
                    acc[s][mt] = (f32x4){bc.x, bc.y, bc.z, bc.w};
                }
            }
        }

#pragma unroll
        for (int kt = 0; kt < 4; ++kt) {
            short8 Eh[2], El[2];
#pragma unroll
            for (int s = 0; s < 2; ++s) {
                const int off = (2 * pA[s] + (kt >> 1)) * ESTR + (kt & 1) * 32 + kg * 8;
                Eh[s] = *(const short8*)&ehl[0][off];
                El[s] = *(const short8*)&ehl[1][off];
            }
#pragma unroll
            for (int mt = 0; mt < 4; ++mt) {
                const short8 wh = w1h[kt * 4 + mt], wl = w1l[kt * 4 + mt];
#pragma unroll
                for (int s = 0; s < 2; ++s) {
                    acc[s][mt] = MFMA(wh, Eh[s], acc[s][mt]);
                    acc[s][mt] = MFMA(wl, Eh[s], acc[s][mt]);
                    acc[s][mt] = MFMA(wh, El[s], acc[s][mt]);
                }
            }
        }

        s4b hh[2][4], hl[2][4];
#pragma unroll
        for (int s = 0; s < 2; ++s)
#pragma unroll
            for (int ks = 0; ks < 4; ++ks)
#pragma unroll
                for (int e2 = 0; e2 < 4; ++e2) {
                    short sh, sl2;
                    splitbf(fmaxf(acc[s][ks][e2], 0.f), sh, sl2);
                    hh[s][ks][e2] = sh; hl[s][ks][e2] = sl2;
                }

        f32x4 o[2][4];
#pragma unroll
        for (int mt2 = 0; mt2 < 4; ++mt2) {
            const f4 bb = LD4(b2 + mt2 * 16 + kg * 4);
#pragma unroll
            for (int s = 0; s < 2; ++s) o[s][mt2] = (f32x4){bb.x, bb.y, bb.z, bb.w};
        }
#pragma unroll
        for (int ks = 0; ks < 4; ++ks)
#pragma unroll
            for (int mt2 = 0; mt2 < 4; ++mt2) {
                const int fo4 = ((ks * 4 + mt2) * 64 + lane) * 4;
                const s4b wh = *(const s4b*)(w2lds + w2b + fo4);
                const s4b wl = *(const s4b*)(w2lds + w2b + 4096 + fo4);
#pragma unroll
                for (int s = 0; s < 2; ++s) {
                    o[s][mt2] = MFMA16(wh, hh[s][ks], o[s][mt2]);
                    o[s][mt2] = MFMA16(wl, hh[s][ks], o[s][mt2]);
                    o[s][mt2] = MFMA16(wh, hl[s][ks], o[s][mt2]);
                }
            }

        int iolA[2], vnA[2];
        uint4 pkh[2][2], pkl[2][2];
#pragma unroll
        for (int s = 0; s < 2; ++s) {
            const int p = pA[s];
            const int j = p & (Lh - 1);
            const int iol = 2 * p - j + (net ? Lh : 0);
            iolA[s] = iol;
            vnA[s]  = net ? v1A[s] : vxA[s];

            float z0 = 0.f, z1 = 0.f;
            union { short sv[16]; uint4 v[2]; } ph, pl;
#pragma unroll
            for (int mt2 = 0; mt2 < 4; ++mt2) {
#pragma unroll
                for (int e2 = 0; e2 < 4; ++e2) {
                    short sh, sl2;
                    splitbf(o[s][mt2][e2], sh, sl2);
                    ph.sv[mt2 * 4 + e2] = sh; pl.sv[mt2 * 4 + e2] = sl2;
                }
                const int f0 = mt2 * 16 + kg * 4;
                const f4 wA = LD4(llr_w + 2 * f0);
                const f4 wB = LD4(llr_w + 2 * f0 + 4);
                z0 += o[s][mt2][0] * wA.x + o[s][mt2][1] * wA.z +
                      o[s][mt2][2] * wB.x + o[s][mt2][3] * wB.z;
                z1 += o[s][mt2][0] * wA.y + o[s][mt2][1] * wA.w +
                      o[s][mt2][2] * wB.y + o[s][mt2][3] * wB.w;
            }
            pkh[s][0] = ph.v[0]; pkh[s][1] = ph.v[1];
            pkl[s][0] = pl.v[0]; pkl[s][1] = pl.v[1];
            z0 += __shfl_xor(z0, 16); z1 += __shfl_xor(z1, 16);
            z0 += __shfl_xor(z0, 32); z1 += __shfl_xor(z1, 32);

            if (kg == 0) {
                const int io = ch * 128 + iol;
                const float zz0 = z0 + llr_b[0], zz1 = z1 + llr_b[1];
                const float m   = fmaxf(zz0, zz1);
                const float ex0 = expf(zz0 - m), ex1 = expf(zz1 - m);
                const float inv = 1.0f / (ex0 + ex1);
                const float p0s = ex0 * inv, p1s = ex1 * inv;
                const float c0  = fminf(fmaxf(p0s, EPS_), 1.0f - EPS_);
                const float c1  = fminf(fmaxf(p1s, EPS_), 1.0f - EPS_);
                const int   lab = net ? (v1A[s] & 1) : vxA[s];
                const float loss = -logf(lab ? c1 : c0);
                loss_out[(b * T_ + t) * N_ + io] = loss;
                pscr[(size_t)(b * T_ + t) * N_ + io] = make_float2(p0s, p1s);
            }
        }
        __syncthreads();   // all e/v reads of this stage complete

#pragma unroll
        for (int s = 0; s < 2; ++s) {
            short* dh = &ehl[0][iolA[s] * ESTR + kg * 16];
            short* dl = &ehl[1][iolA[s] * ESTR + kg * 16];
            *(uint4*)dh       = pkh[s][0];
            *(uint4*)(dh + 8) = pkh[s][1];
            *(uint4*)dl       = pkl[s][0];
            *(uint4*)(dl + 8) = pkl[s][1];
            if (kg == 0) v_lds[iolA[s]] = vnA[s];
        }
        __syncthreads();   // writes visible for next stage
    }
}

// ---------------------------------------------------------------------------
// Final: transpose pscr [b][t][io](2) -> pred [b][io][t][2], both copies.
// ---------------------------------------------------------------------------
__global__ __launch_bounds__(256) void pred_epilogue(
    const float2* __restrict__ pscr,
    float* __restrict__ pred1, float* __restrict__ pred2)
{
    const int idx = blockIdx.x * 256 + threadIdx.x;   // b*N + io
    const int b = idx >> 12, io = idx & (N_ - 1);
    float2 v[T_];
#pragma unroll
    for (int t = 0; t < T_; ++t)
        v[t] = pscr[(size_t)(b * T_ + t) * N_ + io];
    float* d1 = pred1 + (size_t)idx * (T_ * 2);
    float* d2 = pred2 + (size_t)idx * (T_ * 2);
#pragma unroll
    for (int q = 0; q < 6; ++q) {
        const f4 w = make_float4(v[2 * q].x, v[2 * q].y, v[2 * q + 1].x, v[2 * q + 1].y);
        *(f4*)(d1 + 4 * q) = w;
        *(f4*)(d2 + 4 * q) = w;
    }
}

// ---------------------------------------------------------------------------
extern "C" void kernel_launch(void* const* d_in, const int* in_sizes, int n_in,
                              void* d_out, int out_size, void* d_ws, size_t ws_size,
                              hipStream_t stream)
{
    const int*   x      = (const int*)  d_in[0];
    const float* y      = (const float*)d_in[1];
    const float* emb_w1 = (const float*)d_in[2];
    const float* emb_b1 = (const float*)d_in[3];
    const float* emb_w2 = (const float*)d_in[4];
    const float* emb_b2 = (const float*)d_in[5];
    const float* cn_w1  = (const float*)d_in[6];
    const float* cn_b1  = (const float*)d_in[7];
    const float* cn_w2  = (const float*)d_in[8];
    const float* cn_b2  = (const float*)d_in[9];
    const float* bn_w1  = (const float*)d_in[10];
    const float* bn_b1  = (const float*)d_in[11];
    const float* bn_w2  = (const float*)d_in[12];
    const float* bn_b2  = (const float*)d_in[13];
    const float* llr_w  = (const float*)d_in[14];
    const float* llr_b  = (const float*)d_in[15];
    const float* label_emb = (const float*)d_in[16];

    float* out      = (float*)d_out;
    float* loss_out = out;
    float* pred1    = out + (size_t)B_ * T_ * N_;
    float* pred2    = pred1 + (size_t)B_ * N_ * T_ * 2;

    const size_t EPLANE = (size_t)B_ * N_ * D_;
    short* eh_a = (short*)d_ws;
    short* el_a = eh_a + EPLANE;
    short* eh_b = el_a + EPLANE;
    short* el_b = eh_b + EPLANE;
    int*   v_a  = (int*)(el_b + EPLANE);
    int*   v_b  = v_a + B_ * N_;
    float2* pscr = (float2*)(v_b + B_ * N_);
    short* wblob = (short*)(pscr + (size_t)B_ * T_ * N_);
    float* contrib = (float*)(wblob + WBLOB_SHORTS);

    prep_kernel<<<1, 256, 0, stream>>>(
        cn_w1, cn_w2, bn_w1, bn_w2, bn_b1, label_emb, wblob, contrib);

    emb_kernel<<<dim3(B_ * N_ / 128), dim3(256), 0, stream>>>(
        x, y, emb_w1, emb_b1, emb_w2, emb_b2, eh_a, el_a, v_a);

    short* ehc = eh_a; short* elc = el_a; short* ehn = eh_b; short* eln = el_b;
    int* vc = v_a; int* vn = v_b;
    for (int t = 0; t < 5; ++t) {
        stage_kernel<<<dim3(B_ * N_ / 2 / 128), dim3(512), 0, stream>>>(
            ehc, elc, vc, ehn, eln, vn, wblob,
            cn_b1, cn_b2, bn_b2, contrib, llr_w, llr_b,
            loss_out, pscr, t, 11 - t);
        short* t1 = ehc; ehc = ehn; ehn = t1;
        short* t2 = elc; elc = eln; eln = t2;
        int* t3 = vc; vc = vn; vn = t3;
    }

    fused_tail<<<dim3(1024), dim3(256), 0, stream>>>(
        ehc, elc, vc, wblob,
        cn_b1, cn_b2, bn_b2, contrib, llr_w, llr_b,
        loss_out, pscr);

    pred_epilogue<<<dim3(B_ * N_ / 256), dim3(256), 0, stream>>>(
        pscr, pred1, pred2);
}

// Round 13
// 226.697 us; speedup vs baseline: 1.2169x; 1.2169x over previous
//
#include <hip/hip_runtime.h>
#include <math.h>

#define B_ 32
#define N_ 4096
#define D_ 64
#define T_ 12
#define EPS_ 1e-7f
#define PSTR 65
#define ESTR 72   // e-plane LDS row stride in SHORTS (144B, 16B-aligned)

typedef float4 f4;
#define LD4(p) (*(const float4*)(p))

typedef __attribute__((ext_vector_type(8))) short short8;
typedef __attribute__((ext_vector_type(4))) short s4b;
typedef __attribute__((ext_vector_type(4))) float f32x4;
#define MFMA(a, b, c)   __builtin_amdgcn_mfma_f32_16x16x32_bf16(a, b, c, 0, 0, 0)
#define MFMA16(a, b, c) __builtin_amdgcn_mfma_f32_16x16x16bf16_1k(a, b, c, 0, 0, 0)

// weight blob offsets (shorts) in global wblob
#define OFF_C1H 0
#define OFF_C1L 8192
#define OFF_B1H 16384
#define OFF_B1L 24576
#define OFF_C2TH 32768
#define OFF_C2TL 36864
#define OFF_B2TH 40960
#define OFF_B2TL 45056
#define WBLOB_SHORTS 49152

__device__ __forceinline__ float f4c(const float4 v, int q) {
    return q == 0 ? v.x : q == 1 ? v.y : q == 2 ? v.z : v.w;
}
__device__ __forceinline__ void fma8(float (&acc)[8], float a, const float4 w0, const float4 w1) {
    acc[0] = fmaf(a, w0.x, acc[0]); acc[1] = fmaf(a, w0.y, acc[1]);
    acc[2] = fmaf(a, w0.z, acc[2]); acc[3] = fmaf(a, w0.w, acc[3]);
    acc[4] = fmaf(a, w1.x, acc[4]); acc[5] = fmaf(a, w1.y, acc[5]);
    acc[6] = fmaf(a, w1.z, acc[6]); acc[7] = fmaf(a, w1.w, acc[7]);
}

__device__ __forceinline__ void splitbf(float a, short& h, short& l) {
    unsigned x = __float_as_uint(a);
    h = (short)(x >> 16);
    float r = a - __uint_as_float(x & 0xffff0000u);
    l = (short)(__float_as_uint(r) >> 16);
}

// sigma: involutive feature permutation for e-storage (swap bits[5:4]<->[3:2])
__device__ __forceinline__ int sigma_(int f) {
    return (((f >> 2) & 3) << 4) | (((f >> 4) & 3) << 2) | (f & 3);
}

// ---------------------------------------------------------------------------
// Prep: pack weights (hi/lo planes) into one contiguous blob + bn contrib.
// ---------------------------------------------------------------------------
__global__ void prep_kernel(
    const float* __restrict__ cn_w1, const float* __restrict__ cn_w2,
    const float* __restrict__ bn_w1, const float* __restrict__ bn_w2,
    const float* __restrict__ bn_b1, const float* __restrict__ label_emb,
    short* __restrict__ wblob, float* __restrict__ contrib)
{
    const int tid = threadIdx.x;
    for (int idx = tid; idx < 8192; idx += 256) {   // w1 packs (K=128)
        const int e = idx & 7, l = (idx >> 3) & 63, fb = idx >> 9;
        const int kt = fb >> 2, mt = fb & 3;
        const int f_lin = (kt & 1) * 32 + (l >> 4) * 8 + e;
        const int k = (kt >> 1) * 64 + sigma_(f_lin);
        const int n = mt * 16 + (l & 15);
        short h, lo;
        splitbf(cn_w1[k * 64 + n], h, lo);
        wblob[OFF_C1H + idx] = h; wblob[OFF_C1L + idx] = lo;
        splitbf(bn_w1[k * 64 + n], h, lo);
        wblob[OFF_B1H + idx] = h; wblob[OFF_B1L + idx] = lo;
    }
    for (int idx = tid; idx < 4096; idx += 256) {   // w2^T packs (16x16x16 A)
        const int e = idx & 3, l = (idx >> 2) & 63, fb = idx >> 8;
        const int ks = fb >> 2, mt2 = fb & 3;
        const int k = ks * 16 + (l >> 4) * 4 + e;
        const int n = mt2 * 16 + (l & 15);
        short h, lo;
        splitbf(cn_w2[k * 64 + n], h, lo);
        wblob[OFF_C2TH + idx] = h; wblob[OFF_C2TL + idx] = lo;
        splitbf(bn_w2[k * 64 + n], h, lo);
        wblob[OFF_B2TH + idx] = h; wblob[OFF_B2TL + idx] = lo;
    }
    if (tid < 128) {
        const int c = tid >> 6, n = tid & 63;
        float s = bn_b1[n];
        for (int kk = 0; kk < 64; ++kk)
            s = fmaf(label_emb[c * 64 + kk], bn_w1[(128 + kk) * 64 + n], s);
        contrib[c * 64 + n] = s;
    }
}

// ---------------------------------------------------------------------------
// Embedding (fp32 vector). Writes e as bf16 hi/lo planes in sigma order.
// ---------------------------------------------------------------------------
__global__ __launch_bounds__(256, 4) void emb_kernel(
    const int* __restrict__ x, const float* __restrict__ y,
    const float* __restrict__ w1, const float* __restrict__ b1,
    const float* __restrict__ w2, const float* __restrict__ b2,
    short* __restrict__ e_hi, short* __restrict__ e_lo, int* __restrict__ v_out)
{
    __shared__ float h_lds[128 * PSTR];
    const int tid = threadIdx.x;
    const int s   = tid & 7;
    const int g   = tid >> 3;
    const int jj0 = s * 8;
    const int i0  = (blockIdx.x * 32 + g) * 4;

    {
        f4 wa0 = LD4(w1 + jj0),      wa1 = LD4(w1 + jj0 + 4);
        f4 wb0 = LD4(w1 + D_ + jj0), wb1 = LD4(w1 + D_ + jj0 + 4);
        f4 bb0 = LD4(b1 + jj0),      bb1 = LD4(b1 + jj0 + 4);
#pragma unroll
        for (int pp = 0; pp < 4; ++pp) {
            const float2 yv = *(const float2*)(y + 2 * (i0 + pp));
            f4 h0, h1;
            h0.x = fmaxf(fmaf(yv.y, wb0.x, fmaf(yv.x, wa0.x, bb0.x)), 0.f);
            h0.y = fmaxf(fmaf(yv.y, wb0.y, fmaf(yv.x, wa0.y, bb0.y)), 0.f);
            h0.z = fmaxf(fmaf(yv.y, wb0.z, fmaf(yv.x, wa0.z, bb0.z)), 0.f);
            h0.w = fmaxf(fmaf(yv.y, wb0.w, fmaf(yv.x, wa0.w, bb0.w)), 0.f);
            h1.x = fmaxf(fmaf(yv.y, wb1.x, fmaf(yv.x, wa1.x, bb1.x)), 0.f);
            h1.y = fmaxf(fmaf(yv.y, wb1.y, fmaf(yv.x, wa1.y, bb1.y)), 0.f);
            h1.z = fmaxf(fmaf(yv.y, wb1.z, fmaf(yv.x, wa1.z, bb1.z)), 0.f);
            h1.w = fmaxf(fmaf(yv.y, wb1.w, fmaf(yv.x, wa1.w, bb1.w)), 0.f);
            float* hp = h_lds + (g * 4 + pp) * PSTR + jj0;
            *(f4*)hp = h0; *(f4*)(hp + 4) = h1;
        }
    }
    __syncthreads();

    float o[4][8];
    {
        f4 b20 = LD4(b2 + jj0), b21 = LD4(b2 + jj0 + 4);
#pragma unroll
        for (int pp = 0; pp < 4; ++pp) {
            o[pp][0]=b20.x; o[pp][1]=b20.y; o[pp][2]=b20.z; o[pp][3]=b20.w;
            o[pp][4]=b21.x; o[pp][5]=b21.y; o[pp][6]=b21.z; o[pp][7]=b21.w;
        }
    }
#pragma unroll 2
    for (int k4 = 0; k4 < 16; ++k4) {
        const f4 x0 = LD4(h_lds + (g * 4 + 0) * PSTR + 4 * k4);
        const f4 x1 = LD4(h_lds + (g * 4 + 1) * PSTR + 4 * k4);
        const f4 x2 = LD4(h_lds + (g * 4 + 2) * PSTR + 4 * k4);
        const f4 x3 = LD4(h_lds + (g * 4 + 3) * PSTR + 4 * k4);
        const float* wk = w2 + (4 * k4) * D_ + jj0;
#pragma unroll
        for (int q = 0; q < 4; ++q) {
            const f4 wa = LD4(wk + q * D_), wb = LD4(wk + q * D_ + 4);
            fma8(o[0], f4c(x0, q), wa, wb);
            fma8(o[1], f4c(x1, q), wa, wb);
            fma8(o[2], f4c(x2, q), wa, wb);
            fma8(o[3], f4c(x3, q), wa, wb);
        }
    }

    const int sp0 = (((jj0 >> 2) & 3) << 4) | (((jj0 >> 4) & 3) << 2);
    const int sp1 = ((((jj0 + 4) >> 2) & 3) << 4) | ((((jj0 + 4) >> 4) & 3) << 2);
#pragma unroll
    for (int pp = 0; pp < 4; ++pp) {
        const size_t rb = (size_t)(i0 + pp) * D_;
        union { short s[8]; uint2 v[2]; } uh, ul;
#pragma unroll
        for (int q = 0; q < 8; ++q) splitbf(o[pp][q], uh.s[q], ul.s[q]);
        *(uint2*)(e_hi + rb + sp0) = uh.v[0];
        *(uint2*)(e_hi + rb + sp1) = uh.v[1];
        *(uint2*)(e_lo + rb + sp0) = ul.v[0];
        *(uint2*)(e_lo + rb + sp1) = ul.v[1];
    }
    if (s < 4) v_out[i0 + s] = x[i0 + s];
}

// ---------------------------------------------------------------------------
// Global tree stage (t = 0..4): r11-proven version. Full wblob in LDS,
// 512 thr = 8 waves x 32 pairs (both nets per wave), 2 blocks/CU.
// ---------------------------------------------------------------------------
__global__ __launch_bounds__(512, 2) void stage_kernel(
    const short* __restrict__ e_hi, const short* __restrict__ e_lo,
    const int* __restrict__ v_in,
    short* __restrict__ eo_hi, short* __restrict__ eo_lo, int* __restrict__ v_out,
    const short* __restrict__ wblob,
    const float* __restrict__ cn_b1, const float* __restrict__ cn_b2,
    const float* __restrict__ bn_b2, const float* __restrict__ contrib,
    const float* __restrict__ llr_w, const float* __restrict__ llr_b,
    float* __restrict__ loss_out, float2* __restrict__ pscr,
    int t, int log2Lh)
{
    __shared__ short wlds[WBLOB_SHORTS];   // 96 KB
    const int tid = threadIdx.x;
    {
        const uint4* src = (const uint4*)wblob;
        uint4* dst = (uint4*)wlds;
#pragma unroll
        for (int i = 0; i < 12; ++i)
            dst[tid + i * 512] = src[tid + i * 512];
    }
    __syncthreads();

    const int lane = tid & 63;
    const int pr = lane & 15, kg = lane >> 4;
    const int wid = tid >> 6;
    const int P0 = (blockIdx.x * 8 + wid) * 32;
    const int b  = P0 >> 11;
    const int Lh = 1 << log2Lh;

    int v1s[2], vx[2];
#pragma unroll
    for (int s = 0; s < 2; ++s) {
        const int gp = P0 + s * 16 + pr;
        const int2 vv = *(const int2*)(v_in + 2 * gp);
        v1s[s] = vv.y; vx[s] = (vv.x ^ vv.y) & 1;
    }

    f32x4 aC[2][4], aB[2][4];
#pragma unroll
    for (int mt = 0; mt < 4; ++mt) {
        const f4 bc = LD4(cn_b1 + mt * 16 + kg * 4);
#pragma unroll
        for (int s = 0; s < 2; ++s) {
            aC[s][mt] = (f32x4){bc.x, bc.y, bc.z, bc.w};
            const f4 cb = LD4(contrib + vx[s] * 64 + mt * 16 + kg * 4);
            aB[s][mt] = (f32x4){cb.x, cb.y, cb.z, cb.w};
        }
    }

#pragma unroll
    for (int kt = 0; kt < 4; ++kt) {
        short8 Eh[2], El[2];
#pragma unroll
        for (int s = 0; s < 2; ++s) {
            const size_t pos = (size_t)(2 * (P0 + s * 16 + pr) + (kt >> 1));
            const int off = (kt & 1) * 32 + kg * 8;
            Eh[s] = *(const short8*)(e_hi + pos * D_ + off);
            El[s] = *(const short8*)(e_lo + pos * D_ + off);
        }
#pragma unroll
        for (int mt = 0; mt < 4; ++mt) {
            const int fo = ((kt * 4 + mt) * 64 + lane) * 8;
            const short8 wh = *(const short8*)(wlds + OFF_C1H + fo);
            const short8 wl = *(const short8*)(wlds + OFF_C1L + fo);
            const short8 uh = *(const short8*)(wlds + OFF_B1H + fo);
            const short8 ul = *(const short8*)(wlds + OFF_B1L + fo);
#pragma unroll
            for (int s = 0; s < 2; ++s) {
                aC[s][mt] = MFMA(wh, Eh[s], aC[s][mt]);
                aC[s][mt] = MFMA(wl, Eh[s], aC[s][mt]);
                aC[s][mt] = MFMA(wh, El[s], aC[s][mt]);
                aB[s][mt] = MFMA(uh, Eh[s], aB[s][mt]);
                aB[s][mt] = MFMA(ul, Eh[s], aB[s][mt]);
                aB[s][mt] = MFMA(uh, El[s], aB[s][mt]);
            }
        }
    }

#pragma unroll
    for (int net = 0; net < 2; ++net) {
        const int w2h_off = net ? OFF_B2TH : OFF_C2TH;
        const int w2l_off = net ? OFF_B2TL : OFF_C2TL;
        const float* __restrict__ b2 = net ? bn_b2 : cn_b2;

        s4b hh[2][4], hl[2][4];
#pragma unroll
        for (int s = 0; s < 2; ++s)
#pragma unroll
            for (int ks = 0; ks < 4; ++ks) {
                const f32x4 a = net ? aB[s][ks] : aC[s][ks];
#pragma unroll
                for (int e2 = 0; e2 < 4; ++e2) {
                    short sh, sl2;
                    splitbf(fmaxf(a[e2], 0.f), sh, sl2);
                    hh[s][ks][e2] = sh; hl[s][ks][e2] = sl2;
                }
            }

        f32x4 o[2][4];
#pragma unroll
        for (int mt2 = 0; mt2 < 4; ++mt2) {
            const f4 bb = LD4(b2 + mt2 * 16 + kg * 4);
#pragma unroll
            for (int s = 0; s < 2; ++s) o[s][mt2] = (f32x4){bb.x, bb.y, bb.z, bb.w};
        }
#pragma unroll
        for (int ks = 0; ks < 4; ++ks)
#pragma unroll
            for (int mt2 = 0; mt2 < 4; ++mt2) {
                const int fo4 = ((ks * 4 + mt2) * 64 + lane) * 4;
                const s4b wh = *(const s4b*)(wlds + w2h_off + fo4);
                const s4b wl = *(const s4b*)(wlds + w2l_off + fo4);
#pragma unroll
                for (int s = 0; s < 2; ++s) {
                    o[s][mt2] = MFMA16(wh, hh[s][ks], o[s][mt2]);
                    o[s][mt2] = MFMA16(wl, hh[s][ks], o[s][mt2]);
                    o[s][mt2] = MFMA16(wh, hl[s][ks], o[s][mt2]);
                }
            }

#pragma unroll
        for (int s = 0; s < 2; ++s) {
            const int gp = P0 + s * 16 + pr;
            const int P  = gp & 2047;
            const int j  = P & (Lh - 1);
            const int io = 2 * P - j + (net ? Lh : 0);
            const int gout = b * N_ + io;

            float z0 = 0.f, z1 = 0.f;
#pragma unroll
            for (int mt2 = 0; mt2 < 4; ++mt2) {
                const int f0 = mt2 * 16 + kg * 4;
                const f4 wA = LD4(llr_w + 2 * f0);
                const f4 wB = LD4(llr_w + 2 * f0 + 4);
                z0 += o[s][mt2][0] * wA.x + o[s][mt2][1] * wA.z +
                      o[s][mt2][2] * wB.x + o[s][mt2][3] * wB.z;
                z1 += o[s][mt2][0] * wA.y + o[s][mt2][1] * wA.w +
                      o[s][mt2][2] * wB.y + o[s][mt2][3] * wB.w;
            }
            z0 += __shfl_xor(z0, 16); z1 += __shfl_xor(z1, 16);
            z0 += __shfl_xor(z0, 32); z1 += __shfl_xor(z1, 32);

            union { short sv[16]; uint4 v[2]; } ph, pl;
#pragma unroll
            for (int mt2 = 0; mt2 < 4; ++mt2)
#pragma unroll
                for (int e2 = 0; e2 < 4; ++e2) {
                    short sh, sl2;
                    splitbf(o[s][mt2][e2], sh, sl2);
                    ph.sv[mt2 * 4 + e2] = sh; pl.sv[mt2 * 4 + e2] = sl2;
                }
            const size_t eb = (size_t)gout * D_ + kg * 16;
            *(uint4*)(eo_hi + eb)     = ph.v[0];
            *(uint4*)(eo_hi + eb + 8) = ph.v[1];
            *(uint4*)(eo_lo + eb)     = pl.v[0];
            *(uint4*)(eo_lo + eb + 8) = pl.v[1];

            if (kg == 0) {
                v_out[gout] = net ? v1s[s] : vx[s];
                const float zz0 = z0 + llr_b[0], zz1 = z1 + llr_b[1];
                const float m   = fmaxf(zz0, zz1);
                const float ex0 = expf(zz0 - m), ex1 = expf(zz1 - m);
                const float inv = 1.0f / (ex0 + ex1);
                const float p0s = ex0 * inv, p1s = ex1 * inv;
                const float c0  = fminf(fmaxf(p0s, EPS_), 1.0f - EPS_);
                const float c1  = fminf(fmaxf(p1s, EPS_), 1.0f - EPS_);
                const int   lab = net ? (v1s[s] & 1) : vx[s];
                const float loss = -logf(lab ? c1 : c0);
                loss_out[(b * T_ + t) * N_ + io] = loss;
                pscr[(size_t)(b * T_ + t) * N_ + io] = make_float2(p0s, p1s);
            }
        }
    }
}

// ---------------------------------------------------------------------------
// Fused tail (t = 5..11): W1 in registers; LDS = W2 (32KB) + e hi/lo planes
// + v + small constants (contrib/biases/llr). 256 thr = 4 waves x (net, 32
// pairs). ~71 KB -> 2 blocks/CU. All in-loop loads are LDS.
// ---------------------------------------------------------------------------
__global__ __launch_bounds__(256, 2) void fused_tail(
    const short* __restrict__ e_hi, const short* __restrict__ e_lo,
    const int* __restrict__ v_in,
    const short* __restrict__ wblob,
    const float* __restrict__ cn_b1, const float* __restrict__ cn_b2,
    const float* __restrict__ bn_b2, const float* __restrict__ contrib,
    const float* __restrict__ llr_w, const float* __restrict__ llr_b,
    float* __restrict__ loss_out, float2* __restrict__ pscr)
{
    __shared__ __align__(16) short w2lds[16384];       // 32 KB
    __shared__ __align__(16) short ehl[2][128 * ESTR]; // 2 x 18KB hi/lo planes
    __shared__ int v_lds[128];
    __shared__ __align__(16) float cst[448];           // contrib|b1|b2c|b2b|llr
    const int tid = threadIdx.x;
    {
        uint4* dst = (uint4*)w2lds;
        const uint4* src = (const uint4*)(wblob + OFF_C2TH);
#pragma unroll
        for (int i = 0; i < 8; ++i)
            dst[tid + i * 256] = src[tid + i * 256];
    }
    if (tid < 128) { cst[tid] = contrib[tid]; cst[320 + tid] = llr_w[tid]; }
    if (tid < 64) {
        cst[128 + tid] = cn_b1[tid];
        cst[192 + tid] = cn_b2[tid];
        cst[256 + tid] = bn_b2[tid];
    }
    const int b = blockIdx.x >> 5, ch = blockIdx.x & 31;
    const int base_row = b * N_ + ch * 128;
    {
        const int r = tid >> 1, seg = tid & 1;
        const size_t g = (size_t)(base_row + r) * D_ + seg * 32;
#pragma unroll
        for (int pl = 0; pl < 2; ++pl) {
            const short* sp = (pl ? e_lo : e_hi) + g;
            short* dp = &ehl[pl][r * ESTR + seg * 32];
            *(uint4*)dp        = *(const uint4*)sp;
            *(uint4*)(dp + 8)  = *(const uint4*)(sp + 8);
            *(uint4*)(dp + 16) = *(const uint4*)(sp + 16);
            *(uint4*)(dp + 24) = *(const uint4*)(sp + 24);
        }
        if (tid < 128) v_lds[tid] = v_in[base_row + tid];
    }

    const int lane = tid & 63;
    const int pr = lane & 15, kg = lane >> 4;
    const int wid = tid >> 6;
    const int net = wid >> 1, sg = wid & 1;
    const int w2b = net * 8192;

    short8 w1h[16], w1l[16];
    {
        const short* wh = wblob + (net ? OFF_B1H : OFF_C1H);
        const short* wl = wblob + (net ? OFF_B1L : OFF_C1L);
#pragma unroll
        for (int f = 0; f < 16; ++f) {
            const int fo = (f * 64 + lane) * 8;
            w1h[f] = *(const short8*)(wh + fo);
            w1l[f] = *(const short8*)(wl + fo);
        }
    }
    const float* b2c = net ? (cst + 256) : (cst + 192);
    __syncthreads();

    int Lh = 64;
#pragma unroll 1
    for (int t = 5; t < 12; ++t, Lh >>= 1) {
        int pA[2], v1A[2], vxA[2];
        f32x4 acc[2][4];
#pragma unroll
        for (int s = 0; s < 2; ++s) {
            const int p = sg * 32 + s * 16 + pr;
            pA[s] = p;
            const int v0 = v_lds[2 * p], v1 = v_lds[2 * p + 1];
            v1A[s] = v1; vxA[s] = (v0 ^ v1) & 1;
#pragma unroll
            for (int mt = 0; mt < 4; ++mt) {
                if (net) {
                    const f4 cb = LD4(cst + vxA[s] * 64 + mt * 16 + kg * 4);
                    acc[s][mt] = (f32x4){cb.x, cb.y, cb.z, cb.w};
                } else {
                    const f4 bc = LD4(cst + 128 + mt * 16 + kg * 4);
                    acc[s][mt] = (f32x4){bc.x, bc.y, bc.z, bc.w};
                }
            }
        }

#pragma unroll
        for (int kt = 0; kt < 4; ++kt) {
            short8 Eh[2], El[2];
#pragma unroll
            for (int s = 0; s < 2; ++s) {
                const int off = (2 * pA[s] + (kt >> 1)) * ESTR + (kt & 1) * 32 + kg * 8;
                Eh[s] = *(const short8*)&ehl[0][off];
                El[s] = *(const short8*)&ehl[1][off];
            }
#pragma unroll
            for (int mt = 0; mt < 4; ++mt) {
                const short8 wh = w1h[kt * 4 + mt], wl = w1l[kt * 4 + mt];
#pragma unroll
                for (int s = 0; s < 2; ++s) {
                    acc[s][mt] = MFMA(wh, Eh[s], acc[s][mt]);
                    acc[s][mt] = MFMA(wl, Eh[s], acc[s][mt]);
                    acc[s][mt] = MFMA(wh, El[s], acc[s][mt]);
                }
            }
        }

        s4b hh[2][4], hl[2][4];
#pragma unroll
        for (int s = 0; s < 2; ++s)
#pragma unroll
            for (int ks = 0; ks < 4; ++ks)
#pragma unroll
                for (int e2 = 0; e2 < 4; ++e2) {
                    short sh, sl2;
                    splitbf(fmaxf(acc[s][ks][e2], 0.f), sh, sl2);
                    hh[s][ks][e2] = sh; hl[s][ks][e2] = sl2;
                }

        f32x4 o[2][4];
#pragma unroll
        for (int mt2 = 0; mt2 < 4; ++mt2) {
            const f4 bb = LD4(b2c + mt2 * 16 + kg * 4);
#pragma unroll
            for (int s = 0; s < 2; ++s) o[s][mt2] = (f32x4){bb.x, bb.y, bb.z, bb.w};
        }
#pragma unroll
        for (int ks = 0; ks < 4; ++ks)
#pragma unroll
            for (int mt2 = 0; mt2 < 4; ++mt2) {
                const int fo4 = ((ks * 4 + mt2) * 64 + lane) * 4;
                const s4b wh = *(const s4b*)(w2lds + w2b + fo4);
                const s4b wl = *(const s4b*)(w2lds + w2b + 4096 + fo4);
#pragma unroll
                for (int s = 0; s < 2; ++s) {
                    o[s][mt2] = MFMA16(wh, hh[s][ks], o[s][mt2]);
                    o[s][mt2] = MFMA16(wl, hh[s][ks], o[s][mt2]);
                    o[s][mt2] = MFMA16(wh, hl[s][ks], o[s][mt2]);
                }
            }

        int iolA[2], vnA[2];
        uint4 pkh[2][2], pkl[2][2];
#pragma unroll
        for (int s = 0; s < 2; ++s) {
            const int p = pA[s];
            const int j = p & (Lh - 1);
            const int iol = 2 * p - j + (net ? Lh : 0);
            iolA[s] = iol;
            vnA[s]  = net ? v1A[s] : vxA[s];

            float z0 = 0.f, z1 = 0.f;
            union { short sv[16]; uint4 v[2]; } ph, pl;
#pragma unroll
            for (int mt2 = 0; mt2 < 4; ++mt2) {
#pragma unroll
                for (int e2 = 0; e2 < 4; ++e2) {
                    short sh, sl2;
                    splitbf(o[s][mt2][e2], sh, sl2);
                    ph.sv[mt2 * 4 + e2] = sh; pl.sv[mt2 * 4 + e2] = sl2;
                }
                const int f0 = mt2 * 16 + kg * 4;
                const f4 wA = LD4(cst + 320 + 2 * f0);
                const f4 wB = LD4(cst + 320 + 2 * f0 + 4);
                z0 += o[s][mt2][0] * wA.x + o[s][mt2][1] * wA.z +
                      o[s][mt2][2] * wB.x + o[s][mt2][3] * wB.z;
                z1 += o[s][mt2][0] * wA.y + o[s][mt2][1] * wA.w +
                      o[s][mt2][2] * wB.y + o[s][mt2][3] * wB.w;
            }
            pkh[s][0] = ph.v[0]; pkh[s][1] = ph.v[1];
            pkl[s][0] = pl.v[0]; pkl[s][1] = pl.v[1];
            z0 += __shfl_xor(z0, 16); z1 += __shfl_xor(z1, 16);
            z0 += __shfl_xor(z0, 32); z1 += __shfl_xor(z1, 32);

            if (kg == 0) {
                const int io = ch * 128 + iol;
                const float zz0 = z0 + llr_b[0], zz1 = z1 + llr_b[1];
                const float m   = fmaxf(zz0, zz1);
                const float ex0 = expf(zz0 - m), ex1 = expf(zz1 - m);
                const float inv = 1.0f / (ex0 + ex1);
                const float p0s = ex0 * inv, p1s = ex1 * inv;
                const float c0  = fminf(fmaxf(p0s, EPS_), 1.0f - EPS_);
                const float c1  = fminf(fmaxf(p1s, EPS_), 1.0f - EPS_);
                const int   lab = net ? (v1A[s] & 1) : vxA[s];
                const float loss = -logf(lab ? c1 : c0);
                loss_out[(b * T_ + t) * N_ + io] = loss;
                pscr[(size_t)(b * T_ + t) * N_ + io] = make_float2(p0s, p1s);
            }
        }
        __syncthreads();   // all e/v reads of this stage complete

#pragma unroll
        for (int s = 0; s < 2; ++s) {
            short* dh = &ehl[0][iolA[s] * ESTR + kg * 16];
            short* dl = &ehl[1][iolA[s] * ESTR + kg * 16];
            *(uint4*)dh       = pkh[s][0];
            *(uint4*)(dh + 8) = pkh[s][1];
            *(uint4*)dl       = pkl[s][0];
            *(uint4*)(dl + 8) = pkl[s][1];
            if (kg == 0) v_lds[iolA[s]] = vnA[s];
        }
        __syncthreads();   // writes visible for next stage
    }
}

// ---------------------------------------------------------------------------
// Final: transpose pscr [b][t][io](2) -> pred [b][io][t][2], both copies.
// ---------------------------------------------------------------------------
__global__ __launch_bounds__(256) void pred_epilogue(
    const float2* __restrict__ pscr,
    float* __restrict__ pred1, float* __restrict__ pred2)
{
    const int idx = blockIdx.x * 256 + threadIdx.x;   // b*N + io
    const int b = idx >> 12, io = idx & (N_ - 1);
    float2 v[T_];
#pragma unroll
    for (int t = 0; t < T_; ++t)
        v[t] = pscr[(size_t)(b * T_ + t) * N_ + io];
    float* d1 = pred1 + (size_t)idx * (T_ * 2);
    float* d2 = pred2 + (size_t)idx * (T_ * 2);
#pragma unroll
    for (int q = 0; q < 6; ++q) {
        const f4 w = make_float4(v[2 * q].x, v[2 * q].y, v[2 * q + 1].x, v[2 * q + 1].y);
        *(f4*)(d1 + 4 * q) = w;
        *(f4*)(d2 + 4 * q) = w;
    }
}

// ---------------------------------------------------------------------------
extern "C" void kernel_launch(void* const* d_in, const int* in_sizes, int n_in,
                              void* d_out, int out_size, void* d_ws, size_t ws_size,
                              hipStream_t stream)
{
    const int*   x      = (const int*)  d_in[0];
    const float* y      = (const float*)d_in[1];
    const float* emb_w1 = (const float*)d_in[2];
    const float* emb_b1 = (const float*)d_in[3];
    const float* emb_w2 = (const float*)d_in[4];
    const float* emb_b2 = (const float*)d_in[5];
    const float* cn_w1  = (const float*)d_in[6];
    const float* cn_b1  = (const float*)d_in[7];
    const float* cn_w2  = (const float*)d_in[8];
    const float* cn_b2  = (const float*)d_in[9];
    const float* bn_w1  = (const float*)d_in[10];
    const float* bn_b1  = (const float*)d_in[11];
    const float* bn_w2  = (const float*)d_in[12];
    const float* bn_b2  = (const float*)d_in[13];
    const float* llr_w  = (const float*)d_in[14];
    const float* llr_b  = (const float*)d_in[15];
    const float* label_emb = (const float*)d_in[16];

    float* out      = (float*)d_out;
    float* loss_out = out;
    float* pred1    = out + (size_t)B_ * T_ * N_;
    float* pred2    = pred1 + (size_t)B_ * N_ * T_ * 2;

    const size_t EPLANE = (size_t)B_ * N_ * D_;
    short* eh_a = (short*)d_ws;
    short* el_a = eh_a + EPLANE;
    short* eh_b = el_a + EPLANE;
    short* el_b = eh_b + EPLANE;
    int*   v_a  = (int*)(el_b + EPLANE);
    int*   v_b  = v_a + B_ * N_;
    float2* pscr = (float2*)(v_b + B_ * N_);
    short* wblob = (short*)(pscr + (size_t)B_ * T_ * N_);
    float* contrib = (float*)(wblob + WBLOB_SHORTS);

    prep_kernel<<<1, 256, 0, stream>>>(
        cn_w1, cn_w2, bn_w1, bn_w2, bn_b1, label_emb, wblob, contrib);

    emb_kernel<<<dim3(B_ * N_ / 128), dim3(256), 0, stream>>>(
        x, y, emb_w1, emb_b1, emb_w2, emb_b2, eh_a, el_a, v_a);

    short* ehc = eh_a; short* elc = el_a; short* ehn = eh_b; short* eln = el_b;
    int* vc = v_a; int* vn = v_b;
    for (int t = 0; t < 5; ++t) {
        stage_kernel<<<dim3(B_ * N_ / 2 / 256), dim3(512), 0, stream>>>(
            ehc, elc, vc, ehn, eln, vn, wblob,
            cn_b1, cn_b2, bn_b2, contrib, llr_w, llr_b,
            loss_out, pscr, t, 11 - t);
        short* t1 = ehc; ehc = ehn; ehn = t1;
        short* t2 = elc; elc = eln; eln = t2;
        int* t3 = vc; vc = vn; vn = t3;
    }

    fused_tail<<<dim3(1024), dim3(256), 0, stream>>>(
        ehc, elc, vc, wblob,
        cn_b1, cn_b2, bn_b2, contrib, llr_w, llr_b,
        loss_out, pscr);

    pred_epilogue<<<dim3(B_ * N_ / 256), dim3(256), 0, stream>>>(
        pscr, pred1, pred2);
}

// Round 14
// 216.178 us; speedup vs baseline: 1.2762x; 1.0487x over previous
//
#include <hip/hip_runtime.h>
#include <math.h>

#define B_ 32
#define N_ 4096
#define D_ 64
#define T_ 12
#define EPS_ 1e-7f
#define PSTR 65
#define ESTR 72   // e-plane LDS row stride in SHORTS (144B, 16B-aligned)

typedef float4 f4;
#define LD4(p) (*(const float4*)(p))

typedef __attribute__((ext_vector_type(8))) short short8;
typedef __attribute__((ext_vector_type(4))) short s4b;
typedef __attribute__((ext_vector_type(4))) float f32x4;
#define MFMA(a, b, c)   __builtin_amdgcn_mfma_f32_16x16x32_bf16(a, b, c, 0, 0, 0)
#define MFMA16(a, b, c) __builtin_amdgcn_mfma_f32_16x16x16bf16_1k(a, b, c, 0, 0, 0)

// weight blob offsets (shorts) in global wblob
#define OFF_C1H 0
#define OFF_C1L 8192
#define OFF_B1H 16384
#define OFF_B1L 24576
#define OFF_C2TH 32768
#define OFF_C2TL 36864
#define OFF_B2TH 40960
#define OFF_B2TL 45056
#define WBLOB_SHORTS 49152

__device__ __forceinline__ float f4c(const float4 v, int q) {
    return q == 0 ? v.x : q == 1 ? v.y : q == 2 ? v.z : v.w;
}
__device__ __forceinline__ void fma8(float (&acc)[8], float a, const float4 w0, const float4 w1) {
    acc[0] = fmaf(a, w0.x, acc[0]); acc[1] = fmaf(a, w0.y, acc[1]);
    acc[2] = fmaf(a, w0.z, acc[2]); acc[3] = fmaf(a, w0.w, acc[3]);
    acc[4] = fmaf(a, w1.x, acc[4]); acc[5] = fmaf(a, w1.y, acc[5]);
    acc[6] = fmaf(a, w1.z, acc[6]); acc[7] = fmaf(a, w1.w, acc[7]);
}

__device__ __forceinline__ void splitbf(float a, short& h, short& l) {
    unsigned x = __float_as_uint(a);
    h = (short)(x >> 16);
    float r = a - __uint_as_float(x & 0xffff0000u);
    l = (short)(__float_as_uint(r) >> 16);
}

// sigma: involutive feature permutation for e-storage (swap bits[5:4]<->[3:2])
__device__ __forceinline__ int sigma_(int f) {
    return (((f >> 2) & 3) << 4) | (((f >> 4) & 3) << 2) | (f & 3);
}

// ---------------------------------------------------------------------------
// Prep (parallel): blocks 0-31 w1 packs, 32-47 w2^T packs, 48 contrib.
// ---------------------------------------------------------------------------
__global__ void prep_kernel(
    const float* __restrict__ cn_w1, const float* __restrict__ cn_w2,
    const float* __restrict__ bn_w1, const float* __restrict__ bn_w2,
    const float* __restrict__ bn_b1, const float* __restrict__ label_emb,
    short* __restrict__ wblob, float* __restrict__ contrib)
{
    const int bid = blockIdx.x, tid = threadIdx.x;
    if (bid < 32) {                                  // w1 packs (K=128)
        const int idx = bid * 256 + tid;
        const int e = idx & 7, l = (idx >> 3) & 63, fb = idx >> 9;
        const int kt = fb >> 2, mt = fb & 3;
        const int f_lin = (kt & 1) * 32 + (l >> 4) * 8 + e;
        const int k = (kt >> 1) * 64 + sigma_(f_lin);
        const int n = mt * 16 + (l & 15);
        short h, lo;
        splitbf(cn_w1[k * 64 + n], h, lo);
        wblob[OFF_C1H + idx] = h; wblob[OFF_C1L + idx] = lo;
        splitbf(bn_w1[k * 64 + n], h, lo);
        wblob[OFF_B1H + idx] = h; wblob[OFF_B1L + idx] = lo;
    } else if (bid < 48) {                           // w2^T packs (16x16x16 A)
        const int idx = (bid - 32) * 256 + tid;
        const int e = idx & 3, l = (idx >> 2) & 63, fb = idx >> 8;
        const int ks = fb >> 2, mt2 = fb & 3;
        const int k = ks * 16 + (l >> 4) * 4 + e;
        const int n = mt2 * 16 + (l & 15);
        short h, lo;
        splitbf(cn_w2[k * 64 + n], h, lo);
        wblob[OFF_C2TH + idx] = h; wblob[OFF_C2TL + idx] = lo;
        splitbf(bn_w2[k * 64 + n], h, lo);
        wblob[OFF_B2TH + idx] = h; wblob[OFF_B2TL + idx] = lo;
    } else if (tid < 128) {                          // contrib
        const int c = tid >> 6, n = tid & 63;
        float s = bn_b1[n];
#pragma unroll 8
        for (int kk = 0; kk < 64; ++kk)
            s = fmaf(label_emb[c * 64 + kk], bn_w1[(128 + kk) * 64 + n], s);
        contrib[c * 64 + n] = s;
    }
}

// ---------------------------------------------------------------------------
// Embedding (fp32 vector, w2 staged in LDS). Writes e planes in sigma order.
// ---------------------------------------------------------------------------
__global__ __launch_bounds__(256, 3) void emb_kernel(
    const int* __restrict__ x, const float* __restrict__ y,
    const float* __restrict__ w1, const float* __restrict__ b1,
    const float* __restrict__ w2, const float* __restrict__ b2,
    short* __restrict__ e_hi, short* __restrict__ e_lo, int* __restrict__ v_out)
{
    __shared__ float h_lds[128 * PSTR];
    __shared__ __align__(16) float w2s[4096];   // 16 KB
    const int tid = threadIdx.x;
    const int s   = tid & 7;
    const int g   = tid >> 3;
    const int jj0 = s * 8;
    const int i0  = (blockIdx.x * 32 + g) * 4;

    {   // stage w2 into LDS (covered by the barrier below)
        float4* d = (float4*)w2s;
        const float4* sp = (const float4*)w2;
#pragma unroll
        for (int i = 0; i < 4; ++i)
            d[tid + i * 256] = sp[tid + i * 256];
    }

    {
        f4 wa0 = LD4(w1 + jj0),      wa1 = LD4(w1 + jj0 + 4);
        f4 wb0 = LD4(w1 + D_ + jj0), wb1 = LD4(w1 + D_ + jj0 + 4);
        f4 bb0 = LD4(b1 + jj0),      bb1 = LD4(b1 + jj0 + 4);
#pragma unroll
        for (int pp = 0; pp < 4; ++pp) {
            const float2 yv = *(const float2*)(y + 2 * (i0 + pp));
            f4 h0, h1;
            h0.x = fmaxf(fmaf(yv.y, wb0.x, fmaf(yv.x, wa0.x, bb0.x)), 0.f);
            h0.y = fmaxf(fmaf(yv.y, wb0.y, fmaf(yv.x, wa0.y, bb0.y)), 0.f);
            h0.z = fmaxf(fmaf(yv.y, wb0.z, fmaf(yv.x, wa0.z, bb0.z)), 0.f);
            h0.w = fmaxf(fmaf(yv.y, wb0.w, fmaf(yv.x, wa0.w, bb0.w)), 0.f);
            h1.x = fmaxf(fmaf(yv.y, wb1.x, fmaf(yv.x, wa1.x, bb1.x)), 0.f);
            h1.y = fmaxf(fmaf(yv.y, wb1.y, fmaf(yv.x, wa1.y, bb1.y)), 0.f);
            h1.z = fmaxf(fmaf(yv.y, wb1.z, fmaf(yv.x, wa1.z, bb1.z)), 0.f);
            h1.w = fmaxf(fmaf(yv.y, wb1.w, fmaf(yv.x, wa1.w, bb1.w)), 0.f);
            float* hp = h_lds + (g * 4 + pp) * PSTR + jj0;
            *(f4*)hp = h0; *(f4*)(hp + 4) = h1;
        }
    }
    __syncthreads();

    float o[4][8];
    {
        f4 b20 = LD4(b2 + jj0), b21 = LD4(b2 + jj0 + 4);
#pragma unroll
        for (int pp = 0; pp < 4; ++pp) {
            o[pp][0]=b20.x; o[pp][1]=b20.y; o[pp][2]=b20.z; o[pp][3]=b20.w;
            o[pp][4]=b21.x; o[pp][5]=b21.y; o[pp][6]=b21.z; o[pp][7]=b21.w;
        }
    }
#pragma unroll 2
    for (int k4 = 0; k4 < 16; ++k4) {
        const f4 x0 = LD4(h_lds + (g * 4 + 0) * PSTR + 4 * k4);
        const f4 x1 = LD4(h_lds + (g * 4 + 1) * PSTR + 4 * k4);
        const f4 x2 = LD4(h_lds + (g * 4 + 2) * PSTR + 4 * k4);
        const f4 x3 = LD4(h_lds + (g * 4 + 3) * PSTR + 4 * k4);
        const float* wk = w2s + (4 * k4) * D_ + jj0;
#pragma unroll
        for (int q = 0; q < 4; ++q) {
            const f4 wa = LD4(wk + q * D_), wb = LD4(wk + q * D_ + 4);
            fma8(o[0], f4c(x0, q), wa, wb);
            fma8(o[1], f4c(x1, q), wa, wb);
            fma8(o[2], f4c(x2, q), wa, wb);
            fma8(o[3], f4c(x3, q), wa, wb);
        }
    }

    const int sp0 = (((jj0 >> 2) & 3) << 4) | (((jj0 >> 4) & 3) << 2);
    const int sp1 = ((((jj0 + 4) >> 2) & 3) << 4) | ((((jj0 + 4) >> 4) & 3) << 2);
#pragma unroll
    for (int pp = 0; pp < 4; ++pp) {
        const size_t rb = (size_t)(i0 + pp) * D_;
        union { short s[8]; uint2 v[2]; } uh, ul;
#pragma unroll
        for (int q = 0; q < 8; ++q) splitbf(o[pp][q], uh.s[q], ul.s[q]);
        *(uint2*)(e_hi + rb + sp0) = uh.v[0];
        *(uint2*)(e_hi + rb + sp1) = uh.v[1];
        *(uint2*)(e_lo + rb + sp0) = ul.v[0];
        *(uint2*)(e_lo + rb + sp1) = ul.v[1];
    }
    if (s < 4) v_out[i0 + s] = x[i0 + s];
}

// ---------------------------------------------------------------------------
// Global tree stage (t = 0..4): r11-proven version. Full wblob in LDS,
// 512 thr = 8 waves x 32 pairs (both nets per wave), 2 blocks/CU.
// ---------------------------------------------------------------------------
__global__ __launch_bounds__(512, 2) void stage_kernel(
    const short* __restrict__ e_hi, const short* __restrict__ e_lo,
    const int* __restrict__ v_in,
    short* __restrict__ eo_hi, short* __restrict__ eo_lo, int* __restrict__ v_out,
    const short* __restrict__ wblob,
    const float* __restrict__ cn_b1, const float* __restrict__ cn_b2,
    const float* __restrict__ bn_b2, const float* __restrict__ contrib,
    const float* __restrict__ llr_w, const float* __restrict__ llr_b,
    float* __restrict__ loss_out, float2* __restrict__ pscr,
    int t, int log2Lh)
{
    __shared__ short wlds[WBLOB_SHORTS];   // 96 KB
    const int tid = threadIdx.x;
    {
        const uint4* src = (const uint4*)wblob;
        uint4* dst = (uint4*)wlds;
#pragma unroll
        for (int i = 0; i < 12; ++i)
            dst[tid + i * 512] = src[tid + i * 512];
    }
    __syncthreads();

    const int lane = tid & 63;
    const int pr = lane & 15, kg = lane >> 4;
    const int wid = tid >> 6;
    const int P0 = (blockIdx.x * 8 + wid) * 32;
    const int b  = P0 >> 11;
    const int Lh = 1 << log2Lh;

    int v1s[2], vx[2];
#pragma unroll
    for (int s = 0; s < 2; ++s) {
        const int gp = P0 + s * 16 + pr;
        const int2 vv = *(const int2*)(v_in + 2 * gp);
        v1s[s] = vv.y; vx[s] = (vv.x ^ vv.y) & 1;
    }

    f32x4 aC[2][4], aB[2][4];
#pragma unroll
    for (int mt = 0; mt < 4; ++mt) {
        const f4 bc = LD4(cn_b1 + mt * 16 + kg * 4);
#pragma unroll
        for (int s = 0; s < 2; ++s) {
            aC[s][mt] = (f32x4){bc.x, bc.y, bc.z, bc.w};
            const f4 cb = LD4(contrib + vx[s] * 64 + mt * 16 + kg * 4);
            aB[s][mt] = (f32x4){cb.x, cb.y, cb.z, cb.w};
        }
    }

#pragma unroll
    for (int kt = 0; kt < 4; ++kt) {
        short8 Eh[2], El[2];
#pragma unroll
        for (int s = 0; s < 2; ++s) {
            const size_t pos = (size_t)(2 * (P0 + s * 16 + pr) + (kt >> 1));
            const int off = (kt & 1) * 32 + kg * 8;
            Eh[s] = *(const short8*)(e_hi + pos * D_ + off);
            El[s] = *(const short8*)(e_lo + pos * D_ + off);
        }
#pragma unroll
        for (int mt = 0; mt < 4; ++mt) {
            const int fo = ((kt * 4 + mt) * 64 + lane) * 8;
            const short8 wh = *(const short8*)(wlds + OFF_C1H + fo);
            const short8 wl = *(const short8*)(wlds + OFF_C1L + fo);
            const short8 uh = *(const short8*)(wlds + OFF_B1H + fo);
            const short8 ul = *(const short8*)(wlds + OFF_B1L + fo);
#pragma unroll
            for (int s = 0; s < 2; ++s) {
                aC[s][mt] = MFMA(wh, Eh[s], aC[s][mt]);
                aC[s][mt] = MFMA(wl, Eh[s], aC[s][mt]);
                aC[s][mt] = MFMA(wh, El[s], aC[s][mt]);
                aB[s][mt] = MFMA(uh, Eh[s], aB[s][mt]);
                aB[s][mt] = MFMA(ul, Eh[s], aB[s][mt]);
                aB[s][mt] = MFMA(uh, El[s], aB[s][mt]);
            }
        }
    }

#pragma unroll
    for (int net = 0; net < 2; ++net) {
        const int w2h_off = net ? OFF_B2TH : OFF_C2TH;
        const int w2l_off = net ? OFF_B2TL : OFF_C2TL;
        const float* __restrict__ b2 = net ? bn_b2 : cn_b2;

        s4b hh[2][4], hl[2][4];
#pragma unroll
        for (int s = 0; s < 2; ++s)
#pragma unroll
            for (int ks = 0; ks < 4; ++ks) {
                const f32x4 a = net ? aB[s][ks] : aC[s][ks];
#pragma unroll
                for (int e2 = 0; e2 < 4; ++e2) {
                    short sh, sl2;
                    splitbf(fmaxf(a[e2], 0.f), sh, sl2);
                    hh[s][ks][e2] = sh; hl[s][ks][e2] = sl2;
                }
            }

        f32x4 o[2][4];
#pragma unroll
        for (int mt2 = 0; mt2 < 4; ++mt2) {
            const f4 bb = LD4(b2 + mt2 * 16 + kg * 4);
#pragma unroll
            for (int s = 0; s < 2; ++s) o[s][mt2] = (f32x4){bb.x, bb.y, bb.z, bb.w};
        }
#pragma unroll
        for (int ks = 0; ks < 4; ++ks)
#pragma unroll
            for (int mt2 = 0; mt2 < 4; ++mt2) {
                const int fo4 = ((ks * 4 + mt2) * 64 + lane) * 4;
                const s4b wh = *(const s4b*)(wlds + w2h_off + fo4);
                const s4b wl = *(const s4b*)(wlds + w2l_off + fo4);
#pragma unroll
                for (int s = 0; s < 2; ++s) {
                    o[s][mt2] = MFMA16(wh, hh[s][ks], o[s][mt2]);
                    o[s][mt2] = MFMA16(wl, hh[s][ks], o[s][mt2]);
                    o[s][mt2] = MFMA16(wh, hl[s][ks], o[s][mt2]);
                }
            }

#pragma unroll
        for (int s = 0; s < 2; ++s) {
            const int gp = P0 + s * 16 + pr;
            const int P  = gp & 2047;
            const int j  = P & (Lh - 1);
            const int io = 2 * P - j + (net ? Lh : 0);
            const int gout = b * N_ + io;

            float z0 = 0.f, z1 = 0.f;
#pragma unroll
            for (int mt2 = 0; mt2 < 4; ++mt2) {
                const int f0 = mt2 * 16 + kg * 4;
                const f4 wA = LD4(llr_w + 2 * f0);
                const f4 wB = LD4(llr_w + 2 * f0 + 4);
                z0 += o[s][mt2][0] * wA.x + o[s][mt2][1] * wA.z +
                      o[s][mt2][2] * wB.x + o[s][mt2][3] * wB.z;
                z1 += o[s][mt2][0] * wA.y + o[s][mt2][1] * wA.w +
                      o[s][mt2][2] * wB.y + o[s][mt2][3] * wB.w;
            }
            z0 += __shfl_xor(z0, 16); z1 += __shfl_xor(z1, 16);
            z0 += __shfl_xor(z0, 32); z1 += __shfl_xor(z1, 32);

            union { short sv[16]; uint4 v[2]; } ph, pl;
#pragma unroll
            for (int mt2 = 0; mt2 < 4; ++mt2)
#pragma unroll
                for (int e2 = 0; e2 < 4; ++e2) {
                    short sh, sl2;
                    splitbf(o[s][mt2][e2], sh, sl2);
                    ph.sv[mt2 * 4 + e2] = sh; pl.sv[mt2 * 4 + e2] = sl2;
                }
            const size_t eb = (size_t)gout * D_ + kg * 16;
            *(uint4*)(eo_hi + eb)     = ph.v[0];
            *(uint4*)(eo_hi + eb + 8) = ph.v[1];
            *(uint4*)(eo_lo + eb)     = pl.v[0];
            *(uint4*)(eo_lo + eb + 8) = pl.v[1];

            if (kg == 0) {
                v_out[gout] = net ? v1s[s] : vx[s];
                const float zz0 = z0 + llr_b[0], zz1 = z1 + llr_b[1];
                const float m   = fmaxf(zz0, zz1);
                const float ex0 = expf(zz0 - m), ex1 = expf(zz1 - m);
                const float inv = 1.0f / (ex0 + ex1);
                const float p0s = ex0 * inv, p1s = ex1 * inv;
                const float c0  = fminf(fmaxf(p0s, EPS_), 1.0f - EPS_);
                const float c1  = fminf(fmaxf(p1s, EPS_), 1.0f - EPS_);
                const int   lab = net ? (v1s[s] & 1) : vx[s];
                const float loss = -logf(lab ? c1 : c0);
                loss_out[(b * T_ + t) * N_ + io] = loss;
                pscr[(size_t)(b * T_ + t) * N_ + io] = make_float2(p0s, p1s);
            }
        }
    }
}

// ---------------------------------------------------------------------------
// Fused tail (t = 5..11): W1 in registers; LDS = W2 (32KB) + e hi/lo planes
// + v + small constants. 256 thr = 4 waves x (net, 32 pairs). 2 blocks/CU.
// ---------------------------------------------------------------------------
__global__ __launch_bounds__(256, 2) void fused_tail(
    const short* __restrict__ e_hi, const short* __restrict__ e_lo,
    const int* __restrict__ v_in,
    const short* __restrict__ wblob,
    const float* __restrict__ cn_b1, const float* __restrict__ cn_b2,
    const float* __restrict__ bn_b2, const float* __restrict__ contrib,
    const float* __restrict__ llr_w, const float* __restrict__ llr_b,
    float* __restrict__ loss_out, float2* __restrict__ pscr)
{
    __shared__ __align__(16) short w2lds[16384];       // 32 KB
    __shared__ __align__(16) short ehl[2][128 * ESTR]; // 2 x 18KB hi/lo planes
    __shared__ int v_lds[128];
    __shared__ __align__(16) float cst[448];           // contrib|b1|b2c|b2b|llr
    const int tid = threadIdx.x;
    {
        uint4* dst = (uint4*)w2lds;
        const uint4* src = (const uint4*)(wblob + OFF_C2TH);
#pragma unroll
        for (int i = 0; i < 8; ++i)
            dst[tid + i * 256] = src[tid + i * 256];
    }
    if (tid < 128) { cst[tid] = contrib[tid]; cst[320 + tid] = llr_w[tid]; }
    if (tid < 64) {
        cst[128 + tid] = cn_b1[tid];
        cst[192 + tid] = cn_b2[tid];
        cst[256 + tid] = bn_b2[tid];
    }
    const int b = blockIdx.x >> 5, ch = blockIdx.x & 31;
    const int base_row = b * N_ + ch * 128;
    {
        const int r = tid >> 1, seg = tid & 1;
        const size_t g = (size_t)(base_row + r) * D_ + seg * 32;
#pragma unroll
        for (int pl = 0; pl < 2; ++pl) {
            const short* sp = (pl ? e_lo : e_hi) + g;
            short* dp = &ehl[pl][r * ESTR + seg * 32];
            *(uint4*)dp        = *(const uint4*)sp;
            *(uint4*)(dp + 8)  = *(const uint4*)(sp + 8);
            *(uint4*)(dp + 16) = *(const uint4*)(sp + 16);
            *(uint4*)(dp + 24) = *(const uint4*)(sp + 24);
        }
        if (tid < 128) v_lds[tid] = v_in[base_row + tid];
    }

    const int lane = tid & 63;
    const int pr = lane & 15, kg = lane >> 4;
    const int wid = tid >> 6;
    const int net = wid >> 1, sg = wid & 1;
    const int w2b = net * 8192;

    short8 w1h[16], w1l[16];
    {
        const short* wh = wblob + (net ? OFF_B1H : OFF_C1H);
        const short* wl = wblob + (net ? OFF_B1L : OFF_C1L);
#pragma unroll
        for (int f = 0; f < 16; ++f) {
            const int fo = (f * 64 + lane) * 8;
            w1h[f] = *(const short8*)(wh + fo);
            w1l[f] = *(const short8*)(wl + fo);
        }
    }
    const float* b2c = net ? (cst + 256) : (cst + 192);
    __syncthreads();

    int Lh = 64;
#pragma unroll 1
    for (int t = 5; t < 12; ++t, Lh >>= 1) {
        int pA[2], v1A[2], vxA[2];
        f32x4 acc[2][4];
#pragma unroll
        for (int s = 0; s < 2; ++s) {
            const int p = sg * 32 + s * 16 + pr;
            pA[s] = p;
            const int v0 = v_lds[2 * p], v1 = v_lds[2 * p + 1];
            v1A[s] = v1; vxA[s] = (v0 ^ v1) & 1;
#pragma unroll
            for (int mt = 0; mt < 4; ++mt) {
                if (net) {
                    const f4 cb = LD4(cst + vxA[s] * 64 + mt * 16 + kg * 4);
                    acc[s][mt] = (f32x4){cb.x, cb.y, cb.z, cb.w};
                } else {
                    const f4 bc = LD4(cst + 128 + mt * 16 + kg * 4);
                    acc[s][mt] = (f32x4){bc.x, bc.y, bc.z, bc.w};
                }
            }
        }

#pragma unroll
        for (int kt = 0; kt < 4; ++kt) {
            short8 Eh[2], El[2];
#pragma unroll
            for (int s = 0; s < 2; ++s) {
                const int off = (2 * pA[s] + (kt >> 1)) * ESTR + (kt & 1) * 32 + kg * 8;
                Eh[s] = *(const short8*)&ehl[0][off];
                El[s] = *(const short8*)&ehl[1][off];
            }
#pragma unroll
            for (int mt = 0; mt < 4; ++mt) {
                const short8 wh = w1h[kt * 4 + mt], wl = w1l[kt * 4 + mt];
#pragma unroll
                for (int s = 0; s < 2; ++s) {
                    acc[s][mt] = MFMA(wh, Eh[s], acc[s][mt]);
                    acc[s][mt] = MFMA(wl, Eh[s], acc[s][mt]);
                    acc[s][mt] = MFMA(wh, El[s], acc[s][mt]);
                }
            }
        }

        s4b hh[2][4], hl[2][4];
#pragma unroll
        for (int s = 0; s < 2; ++s)
#pragma unroll
            for (int ks = 0; ks < 4; ++ks)
#pragma unroll
                for (int e2 = 0; e2 < 4; ++e2) {
                    short sh, sl2;
                    splitbf(fmaxf(acc[s][ks][e2], 0.f), sh, sl2);
                    hh[s][ks][e2] = sh; hl[s][ks][e2] = sl2;
                }

        f32x4 o[2][4];
#pragma unroll
        for (int mt2 = 0; mt2 < 4; ++mt2) {
            const f4 bb = LD4(b2c + mt2 * 16 + kg * 4);
#pragma unroll
            for (int s = 0; s < 2; ++s) o[s][mt2] = (f32x4){bb.x, bb.y, bb.z, bb.w};
        }
#pragma unroll
        for (int ks = 0; ks < 4; ++ks)
#pragma unroll
            for (int mt2 = 0; mt2 < 4; ++mt2) {
                const int fo4 = ((ks * 4 + mt2) * 64 + lane) * 4;
                const s4b wh = *(const s4b*)(w2lds + w2b + fo4);
                const s4b wl = *(const s4b*)(w2lds + w2b + 4096 + fo4);
#pragma unroll
                for (int s = 0; s < 2; ++s) {
                    o[s][mt2] = MFMA16(wh, hh[s][ks], o[s][mt2]);
                    o[s][mt2] = MFMA16(wl, hh[s][ks], o[s][mt2]);
                    o[s][mt2] = MFMA16(wh, hl[s][ks], o[s][mt2]);
                }
            }

        int iolA[2], vnA[2];
        uint4 pkh[2][2], pkl[2][2];
#pragma unroll
        for (int s = 0; s < 2; ++s) {
            const int p = pA[s];
            const int j = p & (Lh - 1);
            const int iol = 2 * p - j + (net ? Lh : 0);
            iolA[s] = iol;
            vnA[s]  = net ? v1A[s] : vxA[s];

            float z0 = 0.f, z1 = 0.f;
            union { short sv[16]; uint4 v[2]; } ph, pl;
#pragma unroll
            for (int mt2 = 0; mt2 < 4; ++mt2) {
#pragma unroll
                for (int e2 = 0; e2 < 4; ++e2) {
                    short sh, sl2;
                    splitbf(o[s][mt2][e2], sh, sl2);
                    ph.sv[mt2 * 4 + e2] = sh; pl.sv[mt2 * 4 + e2] = sl2;
                }
                const int f0 = mt2 * 16 + kg * 4;
                const f4 wA = LD4(cst + 320 + 2 * f0);
                const f4 wB = LD4(cst + 320 + 2 * f0 + 4);
                z0 += o[s][mt2][0] * wA.x + o[s][mt2][1] * wA.z +
                      o[s][mt2][2] * wB.x + o[s][mt2][3] * wB.z;
                z1 += o[s][mt2][0] * wA.y + o[s][mt2][1] * wA.w +
                      o[s][mt2][2] * wB.y + o[s][mt2][3] * wB.w;
            }
            pkh[s][0] = ph.v[0]; pkh[s][1] = ph.v[1];
            pkl[s][0] = pl.v[0]; pkl[s][1] = pl.v[1];
            z0 += __shfl_xor(z0, 16); z1 += __shfl_xor(z1, 16);
            z0 += __shfl_xor(z0, 32); z1 += __shfl_xor(z1, 32);

            if (kg == 0) {
                const int io = ch * 128 + iol;
                const float zz0 = z0 + llr_b[0], zz1 = z1 + llr_b[1];
                const float m   = fmaxf(zz0, zz1);
                const float ex0 = expf(zz0 - m), ex1 = expf(zz1 - m);
                const float inv = 1.0f / (ex0 + ex1);
                const float p0s = ex0 * inv, p1s = ex1 * inv;
                const float c0  = fminf(fmaxf(p0s, EPS_), 1.0f - EPS_);
                const float c1  = fminf(fmaxf(p1s, EPS_), 1.0f - EPS_);
                const int   lab = net ? (v1A[s] & 1) : vxA[s];
                const float loss = -logf(lab ? c1 : c0);
                loss_out[(b * T_ + t) * N_ + io] = loss;
                pscr[(size_t)(b * T_ + t) * N_ + io] = make_float2(p0s, p1s);
            }
        }
        __syncthreads();   // all e/v reads of this stage complete

#pragma unroll
        for (int s = 0; s < 2; ++s) {
            short* dh = &ehl[0][iolA[s] * ESTR + kg * 16];
            short* dl = &ehl[1][iolA[s] * ESTR + kg * 16];
            *(uint4*)dh       = pkh[s][0];
            *(uint4*)(dh + 8) = pkh[s][1];
            *(uint4*)dl       = pkl[s][0];
            *(uint4*)(dl + 8) = pkl[s][1];
            if (kg == 0) v_lds[iolA[s]] = vnA[s];
        }
        __syncthreads();   // writes visible for next stage
    }
}

// ---------------------------------------------------------------------------
// Final: transpose pscr [b][t][io](2) -> pred [b][io][t][2], both copies.
// ---------------------------------------------------------------------------
__global__ __launch_bounds__(256) void pred_epilogue(
    const float2* __restrict__ pscr,
    float* __restrict__ pred1, float* __restrict__ pred2)
{
    const int idx = blockIdx.x * 256 + threadIdx.x;   // b*N + io
    const int b = idx >> 12, io = idx & (N_ - 1);
    float2 v[T_];
#pragma unroll
    for (int t = 0; t < T_; ++t)
        v[t] = pscr[(size_t)(b * T_ + t) * N_ + io];
    float* d1 = pred1 + (size_t)idx * (T_ * 2);
    float* d2 = pred2 + (size_t)idx * (T_ * 2);
#pragma unroll
    for (int q = 0; q < 6; ++q) {
        const f4 w = make_float4(v[2 * q].x, v[2 * q].y, v[2 * q + 1].x, v[2 * q + 1].y);
        *(f4*)(d1 + 4 * q) = w;
        *(f4*)(d2 + 4 * q) = w;
    }
}

// ---------------------------------------------------------------------------
extern "C" void kernel_launch(void* const* d_in, const int* in_sizes, int n_in,
                              void* d_out, int out_size, void* d_ws, size_t ws_size,
                              hipStream_t stream)
{
    const int*   x      = (const int*)  d_in[0];
    const float* y      = (const float*)d_in[1];
    const float* emb_w1 = (const float*)d_in[2];
    const float* emb_b1 = (const float*)d_in[3];
    const float* emb_w2 = (const float*)d_in[4];
    const float* emb_b2 = (const float*)d_in[5];
    const float* cn_w1  = (const float*)d_in[6];
    const float* cn_b1  = (const float*)d_in[7];
    const float* cn_w2  = (const float*)d_in[8];
    const float* cn_b2  = (const float*)d_in[9];
    const float* bn_w1  = (const float*)d_in[10];
    const float* bn_b1  = (const float*)d_in[11];
    const float* bn_w2  = (const float*)d_in[12];
    const float* bn_b2  = (const float*)d_in[13];
    const float* llr_w  = (const float*)d_in[14];
    const float* llr_b  = (const float*)d_in[15];
    const float* label_emb = (const float*)d_in[16];

    float* out      = (float*)d_out;
    float* loss_out = out;
    float* pred1    = out + (size_t)B_ * T_ * N_;
    float* pred2    = pred1 + (size_t)B_ * N_ * T_ * 2;

    const size_t EPLANE = (size_t)B_ * N_ * D_;
    short* eh_a = (short*)d_ws;
    short* el_a = eh_a + EPLANE;
    short* eh_b = el_a + EPLANE;
    short* el_b = eh_b + EPLANE;
    int*   v_a  = (int*)(el_b + EPLANE);
    int*   v_b  = v_a + B_ * N_;
    float2* pscr = (float2*)(v_b + B_ * N_);
    short* wblob = (short*)(pscr + (size_t)B_ * T_ * N_);
    float* contrib = (float*)(wblob + WBLOB_SHORTS);

    prep_kernel<<<dim3(49), dim3(256), 0, stream>>>(
        cn_w1, cn_w2, bn_w1, bn_w2, bn_b1, label_emb, wblob, contrib);

    emb_kernel<<<dim3(B_ * N_ / 128), dim3(256), 0, stream>>>(
        x, y, emb_w1, emb_b1, emb_w2, emb_b2, eh_a, el_a, v_a);

    short* ehc = eh_a; short* elc = el_a; short* ehn = eh_b; short* eln = el_b;
    int* vc = v_a; int* vn = v_b;
    for (int t = 0; t < 5; ++t) {
        stage_kernel<<<dim3(B_ * N_ / 2 / 256), dim3(512), 0, stream>>>(
            ehc, elc, vc, ehn, eln, vn, wblob,
            cn_b1, cn_b2, bn_b2, contrib, llr_w, llr_b,
            loss_out, pscr, t, 11 - t);
        short* t1 = ehc; ehc = ehn; ehn = t1;
        short* t2 = elc; elc = eln; eln = t2;
        int* t3 = vc; vc = vn; vn = t3;
    }

    fused_tail<<<dim3(1024), dim3(256), 0, stream>>>(
        ehc, elc, vc, wblob,
        cn_b1, cn_b2, bn_b2, contrib, llr_w, llr_b,
        loss_out, pscr);

    pred_epilogue<<<dim3(B_ * N_ / 256), dim3(256), 0, stream>>>(
        pscr, pred1, pred2);
}